// Round 1
// baseline (719.513 us; speedup 1.0000x reference)
//
#include <hip/hip_runtime.h>
#include <stdint.h>
#include <math.h>

#define T_TOK 1024
#define H_DIM 2048
#define E_NUM 16
#define I_DIM 1408
#define TOPK  4
#define SI_DIM 2816
#define NSLOT (T_TOK * TOPK)

typedef short bf16x8 __attribute__((ext_vector_type(8)));
typedef float f32x4  __attribute__((ext_vector_type(4)));

__device__ __forceinline__ uint16_t f2bf(float f) {
  union { float f; uint32_t u; } c; c.f = f;
  uint32_t u = c.u;
  u += 0x7fffu + ((u >> 16) & 1u);   // RNE
  return (uint16_t)(u >> 16);
}
__device__ __forceinline__ float asf(uint32_t u) {
  union { uint32_t u; float f; } c; c.u = u; return c.f;
}

// ---------------- router: logits -> softmax -> grouped top-k ----------------
__global__ __launch_bounds__(256) void k_router(const float* __restrict__ x,
                                                const float* __restrict__ gw,
                                                int* __restrict__ topk_id,
                                                float* __restrict__ topk_w) {
  int t = blockIdx.x;
  float acc[E_NUM];
#pragma unroll
  for (int e = 0; e < E_NUM; ++e) acc[e] = 0.f;
  for (int h = threadIdx.x; h < H_DIM; h += 256) {
    float xv = x[(long)t * H_DIM + h];
#pragma unroll
    for (int e = 0; e < E_NUM; ++e) acc[e] += xv * gw[e * H_DIM + h];
  }
#pragma unroll
  for (int e = 0; e < E_NUM; ++e) {
#pragma unroll
    for (int off = 32; off; off >>= 1) acc[e] += __shfl_down(acc[e], off);
  }
  __shared__ float part[4][E_NUM];
  int wid = threadIdx.x >> 6, lane = threadIdx.x & 63;
  if (lane == 0) {
#pragma unroll
    for (int e = 0; e < E_NUM; ++e) part[wid][e] = acc[e];
  }
  __syncthreads();
  if (threadIdx.x == 0) {
    float lg[E_NUM], p[E_NUM];
    float m = -1e30f;
    for (int e = 0; e < E_NUM; ++e) {
      lg[e] = part[0][e] + part[1][e] + part[2][e] + part[3][e];
      m = fmaxf(m, lg[e]);
    }
    float s = 0.f;
    for (int e = 0; e < E_NUM; ++e) { p[e] = expf(lg[e] - m); s += p[e]; }
    float inv = 1.f / s;
    for (int e = 0; e < E_NUM; ++e) p[e] *= inv;
    // group scores = max of each group of 4
    float gs[4];
    for (int g = 0; g < 4; ++g) {
      float mg = p[g * 4];
      for (int i = 1; i < 4; ++i) mg = fmaxf(mg, p[g * 4 + i]);
      gs[g] = mg;
    }
    // top-2 groups (ties -> lower index, matches lax.top_k)
    int g1 = 0;
    for (int g = 1; g < 4; ++g) if (gs[g] > gs[g1]) g1 = g;
    int g2 = -1;
    for (int g = 0; g < 4; ++g) {
      if (g == g1) continue;
      if (g2 < 0 || gs[g] > gs[g2]) g2 = g;
    }
    float q[E_NUM];
    for (int e = 0; e < E_NUM; ++e)
      q[e] = ((e >> 2) == g1 || (e >> 2) == g2) ? p[e] : -1e30f;
    int ids[TOPK]; float wv[TOPK]; float wsum = 0.f;
    for (int k = 0; k < TOPK; ++k) {
      int best = 0; float bv = -2e30f;
      for (int e = 0; e < E_NUM; ++e) if (q[e] > bv) { bv = q[e]; best = e; }
      ids[k] = best; wv[k] = p[best]; wsum += p[best]; q[best] = -3e30f;
    }
    float winv = 1.f / wsum;
    for (int k = 0; k < TOPK; ++k) {
      topk_id[t * TOPK + k] = ids[k];
      topk_w[t * TOPK + k] = wv[k] * winv;
    }
  }
}

// ---------------- per-expert counts ----------------
__global__ __launch_bounds__(256) void k_count(const int* __restrict__ topk_id,
                                               int* __restrict__ counts) {
  int e = blockIdx.x, tid = threadIdx.x;
  int c = 0;
  for (int s = tid; s < NSLOT; s += 256) c += (topk_id[s] == e);
#pragma unroll
  for (int off = 32; off; off >>= 1) c += __shfl_down(c, off);
  __shared__ int wsum[4];
  int wid = tid >> 6, lane = tid & 63;
  if (lane == 0) wsum[wid] = c;
  __syncthreads();
  if (tid == 0) counts[e] = wsum[0] + wsum[1] + wsum[2] + wsum[3];
}

__global__ void k_offs(const int* __restrict__ counts, int* __restrict__ offs) {
  if (threadIdx.x == 0 && blockIdx.x == 0) {
    int s = 0;
    for (int e = 0; e < E_NUM; ++e) { offs[e] = s; s += counts[e]; }
    offs[E_NUM] = s;
  }
}

// ---------------- deterministic compaction (block scan, no atomics) --------
__global__ __launch_bounds__(256) void k_fill(const int* __restrict__ topk_id,
                                              const int* __restrict__ offs,
                                              int* __restrict__ tok_of_row,
                                              int* __restrict__ row_of_slot) {
  int e = blockIdx.x, tid = threadIdx.x;
  int t0 = tid * 4;
  int match[4]; int cnt = 0;
#pragma unroll
  for (int i = 0; i < 4; ++i) {
    int t = t0 + i; int mk = -1;
#pragma unroll
    for (int k = 0; k < TOPK; ++k) if (topk_id[t * TOPK + k] == e) mk = k;
    match[i] = mk; cnt += (mk >= 0);
  }
  __shared__ int sc[256];
  sc[tid] = cnt; __syncthreads();
  for (int d = 1; d < 256; d <<= 1) {
    int v = sc[tid];
    if (tid >= d) v += sc[tid - d];
    __syncthreads();
    sc[tid] = v;
    __syncthreads();
  }
  int row = offs[e] + sc[tid] - cnt;
#pragma unroll
  for (int i = 0; i < 4; ++i) {
    if (match[i] >= 0) {
      tok_of_row[row] = t0 + i;
      row_of_slot[(t0 + i) * TOPK + match[i]] = row;
      ++row;
    }
  }
}

// ---------------- x fp32 -> bf16 ----------------
__global__ __launch_bounds__(256) void k_cvt(const float* __restrict__ in,
                                             uint16_t* __restrict__ out) {
  int i = (blockIdx.x * 256 + threadIdx.x) * 4;
  float4 v = *(const float4*)(in + i);
  uint2 p;
  p.x = (uint32_t)f2bf(v.x) | ((uint32_t)f2bf(v.y) << 16);
  p.y = (uint32_t)f2bf(v.z) | ((uint32_t)f2bf(v.w) << 16);
  *(uint2*)(out + i) = p;
}

// ---------------- tiled bf16 MFMA GEMM --------------------------------------
// MODE 0: C = silu(A@Bg) * (A@Bu) -> bf16   (Bu = B cols shifted by up_off)
// MODE 1: C = A@B -> bf16
// MODE 2: C = A@B -> f32
// 64x64 tile, BK=32, 4 waves in 2x2, each wave 32x32 via 2x2 16x16x32 frags.
template <int MODE>
__global__ __launch_bounds__(256) void k_gemm(
    const uint16_t* __restrict__ A, int lda,
    const float* __restrict__ B, int ldb, long b_estride,
    void* __restrict__ Out, int ldo,
    const int* __restrict__ offs,
    const int* __restrict__ rowlist,
    int Mtot, int K, int up_off) {
  int e = blockIdx.z;
  int row_base = 0, row_end = Mtot;
  if (offs) { row_base = offs[e]; row_end = offs[e + 1]; }
  int m0 = row_base + blockIdx.y * 64;
  if (m0 >= row_end) return;
  int n0 = blockIdx.x * 64;
  const float* Bp = B + (long)e * b_estride;

  __shared__ uint16_t As[64][40];
  __shared__ uint16_t Bsg[64][40];
  __shared__ uint16_t Bsu[(MODE == 0) ? 64 : 1][40];

  int tid = threadIdx.x;
  int wid = tid >> 6, lane = tid & 63;
  int wm = (wid >> 1) * 32, wn = (wid & 1) * 32;
  int lrow = lane & 15, kg = lane >> 4;

  f32x4 zero = {0.f, 0.f, 0.f, 0.f};
  f32x4 accg[2][2], accu[2][2];
#pragma unroll
  for (int mi = 0; mi < 2; ++mi)
#pragma unroll
    for (int ni = 0; ni < 2; ++ni) { accg[mi][ni] = zero; accu[mi][ni] = zero; }

  int nk = K >> 5;
  for (int kt = 0; kt < nk; ++kt) {
    __syncthreads();
    // stage A: 64 rows x 32 k (bf16, gathered)
#pragma unroll
    for (int p = 0; p < 2; ++p) {
      int r = p * 32 + (tid >> 3);
      int k4 = (tid & 7) * 4;
      int gr = m0 + r;
      gr = gr < row_end ? gr : row_end - 1;
      int arow = rowlist ? rowlist[gr] : gr;
      *(uint2*)&As[r][k4] =
          *(const uint2*)(A + (long)arow * lda + (kt << 5) + k4);
    }
    // stage B: 32 k x 64 n fp32 -> bf16, transposed into [n][k]
#pragma unroll
    for (int p = 0; p < 2; ++p) {
      int k = p * 16 + (tid >> 4);
      int n4 = (tid & 15) * 4;
      const float* bs = Bp + (long)((kt << 5) + k) * ldb + n0 + n4;
      float4 v = *(const float4*)bs;
      Bsg[n4 + 0][k] = f2bf(v.x);
      Bsg[n4 + 1][k] = f2bf(v.y);
      Bsg[n4 + 2][k] = f2bf(v.z);
      Bsg[n4 + 3][k] = f2bf(v.w);
      if constexpr (MODE == 0) {
        float4 u = *(const float4*)(bs + up_off);
        Bsu[n4 + 0][k] = f2bf(u.x);
        Bsu[n4 + 1][k] = f2bf(u.y);
        Bsu[n4 + 2][k] = f2bf(u.z);
        Bsu[n4 + 3][k] = f2bf(u.w);
      }
    }
    __syncthreads();
    bf16x8 af[2], bg[2], bu[2];
#pragma unroll
    for (int mi = 0; mi < 2; ++mi)
      af[mi] = *(const bf16x8*)&As[wm + mi * 16 + lrow][kg * 8];
#pragma unroll
    for (int ni = 0; ni < 2; ++ni) {
      bg[ni] = *(const bf16x8*)&Bsg[wn + ni * 16 + lrow][kg * 8];
      if constexpr (MODE == 0)
        bu[ni] = *(const bf16x8*)&Bsu[wn + ni * 16 + lrow][kg * 8];
    }
#pragma unroll
    for (int mi = 0; mi < 2; ++mi)
#pragma unroll
      for (int ni = 0; ni < 2; ++ni) {
        accg[mi][ni] = __builtin_amdgcn_mfma_f32_16x16x32_bf16(
            af[mi], bg[ni], accg[mi][ni], 0, 0, 0);
        if constexpr (MODE == 0)
          accu[mi][ni] = __builtin_amdgcn_mfma_f32_16x16x32_bf16(
              af[mi], bu[ni], accu[mi][ni], 0, 0, 0);
      }
  }
  // epilogue: C/D layout col=lane&15, row=(lane>>4)*4+reg (m89-verified)
#pragma unroll
  for (int mi = 0; mi < 2; ++mi)
#pragma unroll
    for (int ni = 0; ni < 2; ++ni)
#pragma unroll
      for (int r = 0; r < 4; ++r) {
        int grow = m0 + wm + mi * 16 + kg * 4 + r;
        if (grow >= row_end) continue;
        int col = n0 + wn + ni * 16 + lrow;
        float g = accg[mi][ni][r];
        if constexpr (MODE == 0) {
          float uu = accu[mi][ni][r];
          float a = g / (1.f + expf(-g)) * uu;
          ((uint16_t*)Out)[(long)grow * ldo + col] = f2bf(a);
        } else if constexpr (MODE == 1) {
          ((uint16_t*)Out)[(long)grow * ldo + col] = f2bf(g);
        } else {
          ((float*)Out)[(long)grow * ldo + col] = g;
        }
      }
}

// ---------------- combine: out += sum_k w_k * y[slot(t,k)] ------------------
__global__ __launch_bounds__(256) void k_combine(float* __restrict__ out,
    const uint16_t* __restrict__ y, const int* __restrict__ row_of_slot,
    const float* __restrict__ topk_w) {
  int t = blockIdx.x, tid = threadIdx.x;
  int h = tid * 8;
  float* op = out + (long)t * H_DIM + h;
  float4 o0 = *(float4*)op;
  float4 o1 = *(float4*)(op + 4);
#pragma unroll
  for (int k = 0; k < TOPK; ++k) {
    int row = row_of_slot[t * TOPK + k];
    float wk = topk_w[t * TOPK + k];
    uint4 v = *(const uint4*)(y + (long)row * H_DIM + h);
    o0.x += wk * asf(v.x << 16); o0.y += wk * asf(v.x & 0xffff0000u);
    o0.z += wk * asf(v.y << 16); o0.w += wk * asf(v.y & 0xffff0000u);
    o1.x += wk * asf(v.z << 16); o1.y += wk * asf(v.z & 0xffff0000u);
    o1.z += wk * asf(v.w << 16); o1.w += wk * asf(v.w & 0xffff0000u);
  }
  *(float4*)op = o0;
  *(float4*)(op + 4) = o1;
}

extern "C" void kernel_launch(void* const* d_in, const int* in_sizes, int n_in,
                              void* d_out, int out_size, void* d_ws,
                              size_t ws_size, hipStream_t stream) {
  const float* x   = (const float*)d_in[0];
  const float* gw  = (const float*)d_in[1];
  const float* wgu = (const float*)d_in[2];
  const float* wd  = (const float*)d_in[3];
  const float* sgu = (const float*)d_in[4];
  const float* sd  = (const float*)d_in[5];
  float* out = (float*)d_out;

  char* ws = (char*)d_ws;
  uint16_t* x_bf     = (uint16_t*)(ws + 0);         //  4.19 MB
  uint16_t* act      = (uint16_t*)(ws + 4194304);   // 11.53 MB (4096 x 1408)
  uint16_t* yslots   = (uint16_t*)(ws + 15728640);  // 16.78 MB (4096 x 2048)
  uint16_t* act_sh   = (uint16_t*)(ws + 32505856);  //  5.77 MB (1024 x 2816)
  int*   topk_id     = (int*)(ws + 38273024);
  float* topk_w      = (float*)(ws + 38289408);
  int*   counts      = (int*)(ws + 38305792);
  int*   offs        = (int*)(ws + 38306048);
  int*   tok_of_row  = (int*)(ws + 38306560);
  int*   row_of_slot = (int*)(ws + 38322944);       // end ~38.34 MB

  k_router<<<T_TOK, 256, 0, stream>>>(x, gw, topk_id, topk_w);
  k_count<<<E_NUM, 256, 0, stream>>>(topk_id, counts);
  k_offs<<<1, 1, 0, stream>>>(counts, offs);
  k_fill<<<E_NUM, 256, 0, stream>>>(topk_id, offs, tok_of_row, row_of_slot);
  k_cvt<<<(T_TOK * H_DIM) / 1024, 256, 0, stream>>>(x, x_bf);

  // routed gate_up + silu*mul -> act[4096][1408]
  k_gemm<0><<<dim3(I_DIM / 64, 16, E_NUM), 256, 0, stream>>>(
      x_bf, H_DIM, wgu, 2 * I_DIM, (long)H_DIM * 2 * I_DIM,
      act, I_DIM, offs, tok_of_row, 0, H_DIM, I_DIM);
  // routed down -> yslots[4096][2048]
  k_gemm<1><<<dim3(H_DIM / 64, 16, E_NUM), 256, 0, stream>>>(
      act, I_DIM, wd, H_DIM, (long)I_DIM * H_DIM,
      yslots, H_DIM, offs, nullptr, 0, I_DIM, 0);
  // shared gate_up + silu*mul -> act_sh[1024][2816]
  k_gemm<0><<<dim3(SI_DIM / 64, T_TOK / 64, 1), 256, 0, stream>>>(
      x_bf, H_DIM, sgu, 2 * SI_DIM, 0,
      act_sh, SI_DIM, nullptr, nullptr, T_TOK, H_DIM, SI_DIM);
  // shared down -> out (f32, overwrites poison fully)
  k_gemm<2><<<dim3(H_DIM / 64, T_TOK / 64, 1), 256, 0, stream>>>(
      act_sh, SI_DIM, sd, H_DIM, 0,
      out, H_DIM, nullptr, nullptr, T_TOK, SI_DIM, 0);
  // add weighted routed slots
  k_combine<<<T_TOK, 256, 0, stream>>>(out, yslots, row_of_slot, topk_w);
}

// Round 2
// 558.431 us; speedup vs baseline: 1.2885x; 1.2885x over previous
//
#include <hip/hip_runtime.h>
#include <hip/hip_bf16.h>
#include <stdint.h>
#include <math.h>

#define T_TOK 1024
#define H_DIM 2048
#define E_NUM 16
#define I_DIM 1408
#define TOPK  4
#define SI_DIM 2816
#define NSLOT (T_TOK * TOPK)

typedef short bf16x8 __attribute__((ext_vector_type(8)));
typedef float f32x4  __attribute__((ext_vector_type(4)));

__device__ __forceinline__ short fbf(float f) {
  __hip_bfloat16 h = __float2bfloat16(f);
  return *reinterpret_cast<short*>(&h);
}
__device__ __forceinline__ float asf(uint32_t u) {
  union { uint32_t u; float f; } c; c.u = u; return c.f;
}

typedef const __attribute__((address_space(1))) char gld_g;
typedef __attribute__((address_space(3))) char gld_l;
__device__ __forceinline__ void gload16(const void* g, void* l) {
  __builtin_amdgcn_global_load_lds((gld_g*)g, (gld_l*)l, 16, 0, 0);
}

// ---------------- router: logits -> softmax -> grouped top-k ----------------
__global__ __launch_bounds__(256) void k_router(const float* __restrict__ x,
                                                const float* __restrict__ gw,
                                                int* __restrict__ topk_id,
                                                float* __restrict__ topk_w) {
  int t = blockIdx.x;
  float acc[E_NUM];
#pragma unroll
  for (int e = 0; e < E_NUM; ++e) acc[e] = 0.f;
  for (int h = threadIdx.x; h < H_DIM; h += 256) {
    float xv = x[(long)t * H_DIM + h];
#pragma unroll
    for (int e = 0; e < E_NUM; ++e) acc[e] += xv * gw[e * H_DIM + h];
  }
#pragma unroll
  for (int e = 0; e < E_NUM; ++e) {
#pragma unroll
    for (int off = 32; off; off >>= 1) acc[e] += __shfl_down(acc[e], off);
  }
  __shared__ float part[4][E_NUM];
  int wid = threadIdx.x >> 6, lane = threadIdx.x & 63;
  if (lane == 0) {
#pragma unroll
    for (int e = 0; e < E_NUM; ++e) part[wid][e] = acc[e];
  }
  __syncthreads();
  if (threadIdx.x == 0) {
    float lg[E_NUM], p[E_NUM];
    float m = -1e30f;
    for (int e = 0; e < E_NUM; ++e) {
      lg[e] = part[0][e] + part[1][e] + part[2][e] + part[3][e];
      m = fmaxf(m, lg[e]);
    }
    float s = 0.f;
    for (int e = 0; e < E_NUM; ++e) { p[e] = expf(lg[e] - m); s += p[e]; }
    float inv = 1.f / s;
    for (int e = 0; e < E_NUM; ++e) p[e] *= inv;
    float gs[4];
    for (int g = 0; g < 4; ++g) {
      float mg = p[g * 4];
      for (int i = 1; i < 4; ++i) mg = fmaxf(mg, p[g * 4 + i]);
      gs[g] = mg;
    }
    int g1 = 0;
    for (int g = 1; g < 4; ++g) if (gs[g] > gs[g1]) g1 = g;
    int g2 = -1;
    for (int g = 0; g < 4; ++g) {
      if (g == g1) continue;
      if (g2 < 0 || gs[g] > gs[g2]) g2 = g;
    }
    float q[E_NUM];
    for (int e = 0; e < E_NUM; ++e)
      q[e] = ((e >> 2) == g1 || (e >> 2) == g2) ? p[e] : -1e30f;
    int ids[TOPK]; float wv[TOPK]; float wsum = 0.f;
    for (int k = 0; k < TOPK; ++k) {
      int best = 0; float bv = -2e30f;
      for (int e = 0; e < E_NUM; ++e) if (q[e] > bv) { bv = q[e]; best = e; }
      ids[k] = best; wv[k] = p[best]; wsum += p[best]; q[best] = -3e30f;
    }
    float winv = 1.f / wsum;
    for (int k = 0; k < TOPK; ++k) {
      topk_id[t * TOPK + k] = ids[k];
      topk_w[t * TOPK + k] = wv[k] * winv;
    }
  }
}

// ---------------- per-expert counts ----------------
__global__ __launch_bounds__(256) void k_count(const int* __restrict__ topk_id,
                                               int* __restrict__ counts) {
  int e = blockIdx.x, tid = threadIdx.x;
  int c = 0;
  for (int s = tid; s < NSLOT; s += 256) c += (topk_id[s] == e);
#pragma unroll
  for (int off = 32; off; off >>= 1) c += __shfl_down(c, off);
  __shared__ int wsum[4];
  int wid = tid >> 6, lane = tid & 63;
  if (lane == 0) wsum[wid] = c;
  __syncthreads();
  if (tid == 0) counts[e] = wsum[0] + wsum[1] + wsum[2] + wsum[3];
}

__global__ void k_offs(const int* __restrict__ counts, int* __restrict__ offs) {
  if (threadIdx.x == 0 && blockIdx.x == 0) {
    int s = 0;
    for (int e = 0; e < E_NUM; ++e) { offs[e] = s; s += counts[e]; }
    offs[E_NUM] = s;
  }
}

// ---------------- deterministic compaction (block scan, no atomics) --------
__global__ __launch_bounds__(256) void k_fill(const int* __restrict__ topk_id,
                                              const int* __restrict__ offs,
                                              int* __restrict__ tok_of_row,
                                              int* __restrict__ row_of_slot) {
  int e = blockIdx.x, tid = threadIdx.x;
  int t0 = tid * 4;
  int match[4]; int cnt = 0;
#pragma unroll
  for (int i = 0; i < 4; ++i) {
    int t = t0 + i; int mk = -1;
#pragma unroll
    for (int k = 0; k < TOPK; ++k) if (topk_id[t * TOPK + k] == e) mk = k;
    match[i] = mk; cnt += (mk >= 0);
  }
  __shared__ int sc[256];
  sc[tid] = cnt; __syncthreads();
  for (int d = 1; d < 256; d <<= 1) {
    int v = sc[tid];
    if (tid >= d) v += sc[tid - d];
    __syncthreads();
    sc[tid] = v;
    __syncthreads();
  }
  int row = offs[e] + sc[tid] - cnt;
#pragma unroll
  for (int i = 0; i < 4; ++i) {
    if (match[i] >= 0) {
      tok_of_row[row] = t0 + i;
      row_of_slot[(t0 + i) * TOPK + match[i]] = row;
      ++row;
    }
  }
}

// ---------------- x fp32 -> bf16 ----------------
__global__ __launch_bounds__(256) void k_cvt(const float* __restrict__ in,
                                             uint16_t* __restrict__ out) {
  int i = (blockIdx.x * 256 + threadIdx.x) * 4;
  float4 v = *(const float4*)(in + i);
  uint2 p;
  p.x = (uint32_t)(uint16_t)fbf(v.x) | ((uint32_t)(uint16_t)fbf(v.y) << 16);
  p.y = (uint32_t)(uint16_t)fbf(v.z) | ((uint32_t)(uint16_t)fbf(v.w) << 16);
  *(uint2*)(out + i) = p;
}

// ---------------- 128x128 MFMA GEMM, fp32-B staged via global_load_lds ------
// MODE 0: C = silu(A@Bg) * (A@Bu) -> bf16   (Bu = B cols shifted by up_off)
// MODE 1: C = A@B -> bf16
// MODE 2: C = A@B -> f32
// Grid is 1D; block -> (mb, nb, e) via bijective chunked XCD swizzle with
// m fastest so m-blocks sharing a B n-panel co-reside on one XCD (L2 reuse).
// LDS: A[128][32] bf16 (8KB) linear; B (and Bu) [32][128] f32 (16KB each)
// with XOR-16-col swizzle keyed on (k>>3)&1 applied on BOTH the per-lane
// global source address and the ds_read address (rule #21).
template <int MODE>
__global__ __launch_bounds__(256, 2) void k_gemm(
    const uint16_t* __restrict__ A, int lda,
    const float* __restrict__ B, int ldb, long bstride,
    void* __restrict__ Out, int ldo,
    const int* __restrict__ offs,
    const int* __restrict__ rowlist,
    int Mtot, int K, int up_off, int NM, int NN) {
  // ---- block swizzle ----
  int NB = gridDim.x;
  int f = blockIdx.x;
  int q = NB >> 3, r = NB & 7;
  int xcd = f & 7, o = f >> 3;
  int f2 = (xcd < r ? xcd * (q + 1) : r * (q + 1) + (xcd - r) * q) + o;
  int mb = f2 % NM;
  int t2 = f2 / NM;
  int nb = t2 % NN;
  int e  = t2 / NN;

  int row_base = 0, row_end = Mtot;
  if (offs) { row_base = offs[e]; row_end = offs[e + 1]; }
  int m0 = row_base + mb * 128;
  if (m0 >= row_end) return;
  int n0 = nb * 128;

  __shared__ char smem[(MODE == 0) ? 40960 : 24576];

  const int tid = threadIdx.x;
  const int wid = tid >> 6, lane = tid & 63;
  const int wm = (wid >> 1) * 64, wn = (wid & 1) * 64;
  const int lrow = lane & 15, kg = lane >> 4;
  const int flip6 = (kg & 1) << 6;

  // ---- staging pointers (advance per k-step) ----
  const char* aSrc[2]; char* aDst[2];
#pragma unroll
  for (int p = 0; p < 2; ++p) {
    int rrow = (wid * 2 + p) * 16 + (lane >> 2);
    int grow = m0 + rrow;
    grow = grow < row_end - 1 ? grow : row_end - 1;
    int arow = rowlist ? rowlist[grow] : grow;
    aSrc[p] = (const char*)(A + (size_t)arow * lda + (lane & 3) * 8);
    aDst[p] = smem + (wid * 2 + p) * 1024;
  }
  const char* bSrc[4]; const char* uSrc[4]; char* bDst[4];
#pragma unroll
  for (int p = 0; p < 4; ++p) {
    int c = wid * 4 + p;
    int k = c * 2 + (lane >> 5);
    int nsw = ((lane & 31) * 4) ^ (((k >> 3) & 1) * 16);
    bSrc[p] = (const char*)(B + (size_t)e * bstride + (size_t)k * ldb + n0 + nsw);
    bDst[p] = smem + 8192 + c * 1024;
    if constexpr (MODE == 0) uSrc[p] = bSrc[p] + (size_t)up_off * 4;
  }

  f32x4 zero = {0.f, 0.f, 0.f, 0.f};
  f32x4 accg[4][4], accu[(MODE == 0) ? 4 : 1][(MODE == 0) ? 4 : 1];
#pragma unroll
  for (int mi = 0; mi < 4; ++mi)
#pragma unroll
    for (int ni = 0; ni < 4; ++ni) {
      accg[mi][ni] = zero;
      if constexpr (MODE == 0) accu[mi][ni] = zero;
    }

  int nk = K >> 5;
  for (int kt = 0; kt < nk; ++kt) {
    __syncthreads();
#pragma unroll
    for (int p = 0; p < 2; ++p) { gload16(aSrc[p], aDst[p]); aSrc[p] += 64; }
#pragma unroll
    for (int p = 0; p < 4; ++p) {
      gload16(bSrc[p], bDst[p]); bSrc[p] += (size_t)ldb * 128;
    }
    if constexpr (MODE == 0) {
#pragma unroll
      for (int p = 0; p < 4; ++p) {
        gload16(uSrc[p], bDst[p] + 16384); uSrc[p] += (size_t)ldb * 128;
      }
    }
    __syncthreads();

    bf16x8 af[4];
#pragma unroll
    for (int mi = 0; mi < 4; ++mi)
      af[mi] = *(const bf16x8*)(smem + (wm + mi * 16 + lrow) * 64 + kg * 16);

#pragma unroll
    for (int ni = 0; ni < 4; ++ni) {
      int ba = 8192 + kg * 4096 + (((wn + ni * 16 + lrow) * 4) ^ flip6);
      bf16x8 bg;
#pragma unroll
      for (int j = 0; j < 8; ++j)
        bg[j] = fbf(*(const float*)(smem + ba + j * 512));
#pragma unroll
      for (int mi = 0; mi < 4; ++mi)
        accg[mi][ni] = __builtin_amdgcn_mfma_f32_16x16x32_bf16(
            af[mi], bg, accg[mi][ni], 0, 0, 0);
      if constexpr (MODE == 0) {
        bf16x8 bu;
#pragma unroll
        for (int j = 0; j < 8; ++j)
          bu[j] = fbf(*(const float*)(smem + 16384 + ba + j * 512));
#pragma unroll
        for (int mi = 0; mi < 4; ++mi)
          accu[mi][ni] = __builtin_amdgcn_mfma_f32_16x16x32_bf16(
              af[mi], bu, accu[mi][ni], 0, 0, 0);
      }
    }
  }

  // epilogue: C/D layout col=lane&15, row=(lane>>4)*4+reg (m89-verified)
#pragma unroll
  for (int mi = 0; mi < 4; ++mi) {
#pragma unroll
    for (int rr = 0; rr < 4; ++rr) {
      int grow = m0 + wm + mi * 16 + kg * 4 + rr;
      if (grow >= row_end) continue;
#pragma unroll
      for (int ni = 0; ni < 4; ++ni) {
        int col = n0 + wn + ni * 16 + lrow;
        float g = accg[mi][ni][rr];
        if constexpr (MODE == 0) {
          float u = accu[mi][ni][rr];
          float a = g / (1.f + __expf(-g)) * u;
          ((uint16_t*)Out)[(size_t)grow * ldo + col] = (uint16_t)fbf(a);
        } else if constexpr (MODE == 1) {
          ((uint16_t*)Out)[(size_t)grow * ldo + col] = (uint16_t)fbf(g);
        } else {
          ((float*)Out)[(size_t)grow * ldo + col] = g;
        }
      }
    }
  }
}

// ---------------- combine: out += sum_k w_k * y[slot(t,k)] ------------------
__global__ __launch_bounds__(256) void k_combine(float* __restrict__ out,
    const uint16_t* __restrict__ y, const int* __restrict__ row_of_slot,
    const float* __restrict__ topk_w) {
  int t = blockIdx.x, tid = threadIdx.x;
  int h = tid * 8;
  float* op = out + (long)t * H_DIM + h;
  float4 o0 = *(float4*)op;
  float4 o1 = *(float4*)(op + 4);
#pragma unroll
  for (int k = 0; k < TOPK; ++k) {
    int row = row_of_slot[t * TOPK + k];
    float wk = topk_w[t * TOPK + k];
    uint4 v = *(const uint4*)(y + (long)row * H_DIM + h);
    o0.x += wk * asf(v.x << 16); o0.y += wk * asf(v.x & 0xffff0000u);
    o0.z += wk * asf(v.y << 16); o0.w += wk * asf(v.y & 0xffff0000u);
    o1.x += wk * asf(v.z << 16); o1.y += wk * asf(v.z & 0xffff0000u);
    o1.z += wk * asf(v.w << 16); o1.w += wk * asf(v.w & 0xffff0000u);
  }
  *(float4*)op = o0;
  *(float4*)(op + 4) = o1;
}

extern "C" void kernel_launch(void* const* d_in, const int* in_sizes, int n_in,
                              void* d_out, int out_size, void* d_ws,
                              size_t ws_size, hipStream_t stream) {
  const float* x   = (const float*)d_in[0];
  const float* gw  = (const float*)d_in[1];
  const float* wgu = (const float*)d_in[2];
  const float* wd  = (const float*)d_in[3];
  const float* sgu = (const float*)d_in[4];
  const float* sd  = (const float*)d_in[5];
  float* out = (float*)d_out;

  char* ws = (char*)d_ws;
  uint16_t* x_bf     = (uint16_t*)(ws + 0);         //  4.19 MB
  uint16_t* act      = (uint16_t*)(ws + 4194304);   // 11.53 MB (4096 x 1408)
  uint16_t* yslots   = (uint16_t*)(ws + 15728640);  // 16.78 MB (4096 x 2048)
  uint16_t* act_sh   = (uint16_t*)(ws + 32505856);  //  5.77 MB (1024 x 2816)
  int*   topk_id     = (int*)(ws + 38273024);
  float* topk_w      = (float*)(ws + 38289408);
  int*   counts      = (int*)(ws + 38305792);
  int*   offs        = (int*)(ws + 38306048);
  int*   tok_of_row  = (int*)(ws + 38306560);
  int*   row_of_slot = (int*)(ws + 38322944);       // end ~38.34 MB

  k_router<<<T_TOK, 256, 0, stream>>>(x, gw, topk_id, topk_w);
  k_count<<<E_NUM, 256, 0, stream>>>(topk_id, counts);
  k_offs<<<1, 1, 0, stream>>>(counts, offs);
  k_fill<<<E_NUM, 256, 0, stream>>>(topk_id, offs, tok_of_row, row_of_slot);
  k_cvt<<<(T_TOK * H_DIM) / 1024, 256, 0, stream>>>(x, x_bf);

  // routed gate_up + silu*mul -> act[4096][1408]
  k_gemm<0><<<11 * 8 * E_NUM, 256, 0, stream>>>(
      x_bf, H_DIM, wgu, 2 * I_DIM, (long)H_DIM * 2 * I_DIM,
      act, I_DIM, offs, tok_of_row, 0, H_DIM, I_DIM, 8, 11);
  // routed down -> yslots[4096][2048]
  k_gemm<1><<<16 * 8 * E_NUM, 256, 0, stream>>>(
      act, I_DIM, wd, H_DIM, (long)I_DIM * H_DIM,
      yslots, H_DIM, offs, nullptr, 0, I_DIM, 0, 8, 16);
  // shared gate_up + silu*mul -> act_sh[1024][2816]
  k_gemm<0><<<22 * 8, 256, 0, stream>>>(
      x_bf, H_DIM, sgu, 2 * SI_DIM, 0,
      act_sh, SI_DIM, nullptr, nullptr, T_TOK, H_DIM, SI_DIM, 8, 22);
  // shared down -> out (f32, overwrites poison fully)
  k_gemm<2><<<16 * 8, 256, 0, stream>>>(
      act_sh, SI_DIM, sd, H_DIM, 0,
      out, H_DIM, nullptr, nullptr, T_TOK, SI_DIM, 0, 8, 16);
  // add weighted routed slots
  k_combine<<<T_TOK, 256, 0, stream>>>(out, yslots, row_of_slot, topk_w);
}

// Round 4
// 412.111 us; speedup vs baseline: 1.7459x; 1.3550x over previous
//
#include <hip/hip_runtime.h>
#include <hip/hip_bf16.h>
#include <stdint.h>
#include <math.h>

#define T_TOK 1024
#define H_DIM 2048
#define E_NUM 16
#define I_DIM 1408
#define TOPK  4
#define SI_DIM 2816
#define NSLOT (T_TOK * TOPK)

typedef short bf16x8 __attribute__((ext_vector_type(8)));
typedef short bf16x4 __attribute__((ext_vector_type(4)));
typedef float f32x4  __attribute__((ext_vector_type(4)));

__device__ __forceinline__ short fbf(float f) {
  __hip_bfloat16 h = __float2bfloat16(f);
  return *reinterpret_cast<short*>(&h);
}
__device__ __forceinline__ float asf(uint32_t u) {
  union { uint32_t u; float f; } c; c.u = u; return c.f;
}

typedef const __attribute__((address_space(1))) char gld_g;
typedef __attribute__((address_space(3))) char gld_l;
__device__ __forceinline__ void gload16(const void* g, void* l) {
  __builtin_amdgcn_global_load_lds((gld_g*)g, (gld_l*)l, 16, 0, 0);
}

// ---------------- router ----------------
__global__ __launch_bounds__(256) void k_router(const float* __restrict__ x,
                                                const float* __restrict__ gw,
                                                int* __restrict__ topk_id,
                                                float* __restrict__ topk_w) {
  int t = blockIdx.x;
  float acc[E_NUM];
#pragma unroll
  for (int e = 0; e < E_NUM; ++e) acc[e] = 0.f;
  for (int h = threadIdx.x; h < H_DIM; h += 256) {
    float xv = x[(long)t * H_DIM + h];
#pragma unroll
    for (int e = 0; e < E_NUM; ++e) acc[e] += xv * gw[e * H_DIM + h];
  }
#pragma unroll
  for (int e = 0; e < E_NUM; ++e) {
#pragma unroll
    for (int off = 32; off; off >>= 1) acc[e] += __shfl_down(acc[e], off);
  }
  __shared__ float part[4][E_NUM];
  int wid = threadIdx.x >> 6, lane = threadIdx.x & 63;
  if (lane == 0) {
#pragma unroll
    for (int e = 0; e < E_NUM; ++e) part[wid][e] = acc[e];
  }
  __syncthreads();
  if (threadIdx.x == 0) {
    float lg[E_NUM], p[E_NUM];
    float m = -1e30f;
    for (int e = 0; e < E_NUM; ++e) {
      lg[e] = part[0][e] + part[1][e] + part[2][e] + part[3][e];
      m = fmaxf(m, lg[e]);
    }
    float s = 0.f;
    for (int e = 0; e < E_NUM; ++e) { p[e] = expf(lg[e] - m); s += p[e]; }
    float inv = 1.f / s;
    for (int e = 0; e < E_NUM; ++e) p[e] *= inv;
    float gs[4];
    for (int g = 0; g < 4; ++g) {
      float mg = p[g * 4];
      for (int i = 1; i < 4; ++i) mg = fmaxf(mg, p[g * 4 + i]);
      gs[g] = mg;
    }
    int g1 = 0;
    for (int g = 1; g < 4; ++g) if (gs[g] > gs[g1]) g1 = g;
    int g2 = -1;
    for (int g = 0; g < 4; ++g) {
      if (g == g1) continue;
      if (g2 < 0 || gs[g] > gs[g2]) g2 = g;
    }
    float q[E_NUM];
    for (int e = 0; e < E_NUM; ++e)
      q[e] = ((e >> 2) == g1 || (e >> 2) == g2) ? p[e] : -1e30f;
    int ids[TOPK]; float wv[TOPK]; float wsum = 0.f;
    for (int k = 0; k < TOPK; ++k) {
      int best = 0; float bv = -2e30f;
      for (int e = 0; e < E_NUM; ++e) if (q[e] > bv) { bv = q[e]; best = e; }
      ids[k] = best; wv[k] = p[best]; wsum += p[best]; q[best] = -3e30f;
    }
    float winv = 1.f / wsum;
    for (int k = 0; k < TOPK; ++k) {
      topk_id[t * TOPK + k] = ids[k];
      topk_w[t * TOPK + k] = wv[k] * winv;
    }
  }
}

// ---------------- per-expert counts ----------------
__global__ __launch_bounds__(256) void k_count(const int* __restrict__ topk_id,
                                               int* __restrict__ counts) {
  int e = blockIdx.x, tid = threadIdx.x;
  int c = 0;
  for (int s = tid; s < NSLOT; s += 256) c += (topk_id[s] == e);
#pragma unroll
  for (int off = 32; off; off >>= 1) c += __shfl_down(c, off);
  __shared__ int wsum[4];
  int wid = tid >> 6, lane = tid & 63;
  if (lane == 0) wsum[wid] = c;
  __syncthreads();
  if (tid == 0) counts[e] = wsum[0] + wsum[1] + wsum[2] + wsum[3];
}

__global__ void k_offs(const int* __restrict__ counts, int* __restrict__ offs,
                       int* __restrict__ cum) {
  if (threadIdx.x == 0 && blockIdx.x == 0) {
    int s = 0, c = 0;
    cum[0] = 0;
    for (int e = 0; e < E_NUM; ++e) {
      offs[e] = s; s += counts[e];
      c += (counts[e] + 127) >> 7;
      cum[e + 1] = c;
    }
    offs[E_NUM] = s;
  }
}

// ---------------- deterministic compaction ----------------
__global__ __launch_bounds__(256) void k_fill(const int* __restrict__ topk_id,
                                              const int* __restrict__ offs,
                                              int* __restrict__ tok_of_row,
                                              int* __restrict__ row_of_slot) {
  int e = blockIdx.x, tid = threadIdx.x;
  int t0 = tid * 4;
  int match[4]; int cnt = 0;
#pragma unroll
  for (int i = 0; i < 4; ++i) {
    int t = t0 + i; int mk = -1;
#pragma unroll
    for (int k = 0; k < TOPK; ++k) if (topk_id[t * TOPK + k] == e) mk = k;
    match[i] = mk; cnt += (mk >= 0);
  }
  __shared__ int sc[256];
  sc[tid] = cnt; __syncthreads();
  for (int d = 1; d < 256; d <<= 1) {
    int v = sc[tid];
    if (tid >= d) v += sc[tid - d];
    __syncthreads();
    sc[tid] = v;
    __syncthreads();
  }
  int row = offs[e] + sc[tid] - cnt;
#pragma unroll
  for (int i = 0; i < 4; ++i) {
    if (match[i] >= 0) {
      tok_of_row[row] = t0 + i;
      row_of_slot[(t0 + i) * TOPK + match[i]] = row;
      ++row;
    }
  }
}

// ---------------- x fp32 -> bf16 ----------------
__global__ __launch_bounds__(256) void k_cvt(const float* __restrict__ in,
                                             uint16_t* __restrict__ out) {
  int i = (blockIdx.x * 256 + threadIdx.x) * 4;
  float4 v = *(const float4*)(in + i);
  uint2 p;
  p.x = (uint32_t)(uint16_t)fbf(v.x) | ((uint32_t)(uint16_t)fbf(v.y) << 16);
  p.y = (uint32_t)(uint16_t)fbf(v.z) | ((uint32_t)(uint16_t)fbf(v.w) << 16);
  *(uint2*)(out + i) = p;
}

// ---------------- 128xBN MFMA GEMM, dbuf, reg-staged B ----------------------
// MODE 0: C = silu(A@Bg)*(A@Bu) -> bf16 ; MODE 1: A@B -> bf16 ; MODE 2: -> f32
// A: [128][32] bf16 LDS, linear, staged via global_load_lds(16B),
//    wave-uniform LDS base (HW adds lane*16).
// B: [BN][32] bf16 LDS, 72B rows, 16B-slot XOR swizzle (slot ^= n&3),
//    reg-staged (4 k-consec fp32 loads -> cvt -> one ds_write_b64).
// One barrier per k-step; prefetch issued before MFMA, LDS-write after (T14).
template <int MODE, int BN>
__global__ __launch_bounds__(256, 3) void k_gemm(
    const uint16_t* __restrict__ A, int lda,
    const float* __restrict__ B, int ldb, long bstride,
    void* __restrict__ Out, int ldo,
    const int* __restrict__ offs, const int* __restrict__ rowlist,
    const int* __restrict__ cum,
    int Mtot, int K, int up_off, int nsplit, long splitelems, int NN) {
  constexpr int MATS = (MODE == 0) ? 2 : 1;
  constexpr int NQUAD = BN / 32;
  constexpr int QN = 256 / BN;
  constexpr int BROW = 72;
  constexpr int HALF = 8192 + MATS * BN * BROW;
  constexpr int NI = BN / 32;
  __shared__ char smem[2 * HALF];

  // ---- block mapping (bijective XCD swizzle, mb fastest) ----
  int NB = gridDim.x;
  int f = blockIdx.x;
  int q8 = NB >> 3, r8 = NB & 7;
  int xcd = f & 7, o = f >> 3;
  int f2 = (xcd < r8 ? xcd * (q8 + 1) : r8 * (q8 + 1) + (xcd - r8) * q8) + o;

  int e = 0, mb = 0, nb = 0, sk = 0;
  int row_base = 0, row_end = Mtot;
  if (offs) {
    for (e = 0; e < E_NUM; ++e) if (f2 < cum[e + 1] * NN) break;
    if (e == E_NUM) return;
    int nmbe = cum[e + 1] - cum[e];
    int loc = f2 - cum[e] * NN;
    mb = loc % nmbe; nb = loc / nmbe;
    row_base = offs[e]; row_end = offs[e + 1];
  } else {
    int nmt = Mtot >> 7;
    mb = f2 % nmt; int rest = f2 / nmt;
    nb = rest % NN; sk = rest / NN;
  }
  int Keff = K / nsplit;
  int kbase = sk * Keff;
  int m0 = row_base + mb * 128;
  int n0 = nb * BN;
  float* outp = (float*)Out + (size_t)sk * splitelems;

  const int tid = threadIdx.x;
  const int wid = tid >> 6, lane = tid & 63;
  const int wm = (wid >> 1) * 64, wn = (wid & 1) * (BN / 2);
  const int lrow = lane & 15, kg = lane >> 4;

  // ---- A staging setup (LDS base wave-uniform; HW adds lane*16) ----
  const uint16_t* aSrc[2]; int aOff[2];
#pragma unroll
  for (int p = 0; p < 2; ++p) {
    int r = (wid * 2 + p) * 16 + (lane >> 2);
    int grow = m0 + r;
    grow = grow < row_end - 1 ? grow : row_end - 1;
    int arow = rowlist ? rowlist[grow] : grow;
    aSrc[p] = A + (size_t)arow * lda + kbase + (lane & 3) * 8;
    aOff[p] = (wid * 2 + p) * 1024;
  }

  // ---- B staging setup ----
  const int nB = tid & (BN - 1);
  const int kq = tid / BN;
  const float* bp[MATS][NQUAD];
  int bOff[MATS][NQUAD];
  {
    const float* Bb = B + (size_t)e * bstride + (size_t)kbase * ldb + n0 + nB;
#pragma unroll
    for (int mat = 0; mat < MATS; ++mat)
#pragma unroll
      for (int q = 0; q < NQUAD; ++q) {
        int k0 = (kq + q * QN) * 4;
        bp[mat][q] = Bb + (size_t)k0 * ldb + (mat ? up_off : 0);
        bOff[mat][q] = 8192 + mat * BN * BROW + nB * BROW +
                       (((k0 >> 3) ^ (nB & 3)) << 4) + ((k0 & 4) << 1);
      }
  }

  auto loadB = [&](float (&v)[MATS][NQUAD][4]) {
#pragma unroll
    for (int mat = 0; mat < MATS; ++mat)
#pragma unroll
      for (int q = 0; q < NQUAD; ++q)
#pragma unroll
        for (int i = 0; i < 4; ++i)
          v[mat][q][i] = bp[mat][q][(size_t)i * ldb];
  };
  auto stageB = [&](int bufbase, float (&v)[MATS][NQUAD][4]) {
#pragma unroll
    for (int mat = 0; mat < MATS; ++mat)
#pragma unroll
      for (int q = 0; q < NQUAD; ++q) {
        uint2 w;
        w.x = (uint32_t)(uint16_t)fbf(v[mat][q][0]) |
              ((uint32_t)(uint16_t)fbf(v[mat][q][1]) << 16);
        w.y = (uint32_t)(uint16_t)fbf(v[mat][q][2]) |
              ((uint32_t)(uint16_t)fbf(v[mat][q][3]) << 16);
        *(uint2*)(smem + bufbase + bOff[mat][q]) = w;
      }
  };
  auto advB = [&]() {
#pragma unroll
    for (int mat = 0; mat < MATS; ++mat)
#pragma unroll
      for (int q = 0; q < NQUAD; ++q) bp[mat][q] += (size_t)32 * ldb;
  };

  f32x4 zero = {0.f, 0.f, 0.f, 0.f};
  f32x4 accg[4][NI];
  f32x4 accu[(MODE == 0) ? 4 : 1][(MODE == 0) ? NI : 1];
#pragma unroll
  for (int mi = 0; mi < 4; ++mi)
#pragma unroll
    for (int ni = 0; ni < NI; ++ni) {
      accg[mi][ni] = zero;
      if constexpr (MODE == 0) accu[mi][ni] = zero;
    }

  // ---- prologue: stage tile 0 into buf0 ----
  {
    float v[MATS][NQUAD][4];
    loadB(v);
#pragma unroll
    for (int p = 0; p < 2; ++p) { gload16(aSrc[p], smem + aOff[p]); aSrc[p] += 32; }
    stageB(0, v);
    advB();
  }
  __syncthreads();

  int nk = Keff >> 5;
  for (int kt = 0; kt < nk; ++kt) {
    int cur = kt & 1;
    const char* base = smem + cur * HALF;
    char* obase = smem + (cur ^ 1) * HALF;
    bool pf = (kt + 1 < nk);
    float v[MATS][NQUAD][4];
    if (pf) {
#pragma unroll
      for (int p = 0; p < 2; ++p) { gload16(aSrc[p], obase + aOff[p]); aSrc[p] += 32; }
      loadB(v);
    }
    bf16x8 af[4];
#pragma unroll
    for (int mi = 0; mi < 4; ++mi)
      af[mi] = *(const bf16x8*)(base + (wm + mi * 16 + lrow) * 64 + kg * 16);
#pragma unroll
    for (int ni = 0; ni < NI; ++ni) {
      int n = wn + ni * 16 + lrow;
      int bo = 8192 + n * BROW + ((kg ^ (n & 3)) << 4);
      bf16x4 g0 = *(const bf16x4*)(base + bo);
      bf16x4 g1 = *(const bf16x4*)(base + bo + 8);
      bf16x8 bg = __builtin_shufflevector(g0, g1, 0, 1, 2, 3, 4, 5, 6, 7);
#pragma unroll
      for (int mi = 0; mi < 4; ++mi)
        accg[mi][ni] = __builtin_amdgcn_mfma_f32_16x16x32_bf16(
            af[mi], bg, accg[mi][ni], 0, 0, 0);
      if constexpr (MODE == 0) {
        bf16x4 u0 = *(const bf16x4*)(base + bo + BN * BROW);
        bf16x4 u1 = *(const bf16x4*)(base + bo + BN * BROW + 8);
        bf16x8 bu = __builtin_shufflevector(u0, u1, 0, 1, 2, 3, 4, 5, 6, 7);
#pragma unroll
        for (int mi = 0; mi < 4; ++mi)
          accu[mi][ni] = __builtin_amdgcn_mfma_f32_16x16x32_bf16(
              af[mi], bu, accu[mi][ni], 0, 0, 0);
      }
    }
    if (pf) { stageB((cur ^ 1) * HALF, v); advB(); }
    __syncthreads();
  }

  // ---- epilogue ----
#pragma unroll
  for (int mi = 0; mi < 4; ++mi) {
#pragma unroll
    for (int rr = 0; rr < 4; ++rr) {
      int grow = m0 + wm + mi * 16 + kg * 4 + rr;
      if (grow >= row_end) continue;
#pragma unroll
      for (int ni = 0; ni < NI; ++ni) {
        int col = n0 + wn + ni * 16 + lrow;
        float g = accg[mi][ni][rr];
        if constexpr (MODE == 0) {
          float u = accu[mi][ni][rr];
          float a = g / (1.f + __expf(-g)) * u;
          ((uint16_t*)Out)[(size_t)grow * ldo + col] = (uint16_t)fbf(a);
        } else if constexpr (MODE == 1) {
          ((uint16_t*)Out)[(size_t)grow * ldo + col] = (uint16_t)fbf(g);
        } else {
          outp[(size_t)grow * ldo + col] = g;
        }
      }
    }
  }
}

// ---------------- combine: out = p0(+p1) + sum_k w_k * y[slot] --------------
__global__ __launch_bounds__(256) void k_combine(float* __restrict__ out,
    const uint16_t* __restrict__ y, const int* __restrict__ row_of_slot,
    const float* __restrict__ topk_w, const float* __restrict__ p0,
    const float* __restrict__ p1) {
  int t = blockIdx.x, tid = threadIdx.x;
  int h = tid * 8;
  size_t off = (size_t)t * H_DIM + h;
  float4 o0 = *(const float4*)(p0 + off);
  float4 o1 = *(const float4*)(p0 + off + 4);
  if (p1) {
    float4 q0 = *(const float4*)(p1 + off);
    float4 q1 = *(const float4*)(p1 + off + 4);
    o0.x += q0.x; o0.y += q0.y; o0.z += q0.z; o0.w += q0.w;
    o1.x += q1.x; o1.y += q1.y; o1.z += q1.z; o1.w += q1.w;
  }
#pragma unroll
  for (int k = 0; k < TOPK; ++k) {
    int row = row_of_slot[t * TOPK + k];
    float wk = topk_w[t * TOPK + k];
    uint4 v = *(const uint4*)(y + (size_t)row * H_DIM + h);
    o0.x += wk * asf(v.x << 16); o0.y += wk * asf(v.x & 0xffff0000u);
    o0.z += wk * asf(v.y << 16); o0.w += wk * asf(v.y & 0xffff0000u);
    o1.x += wk * asf(v.z << 16); o1.y += wk * asf(v.z & 0xffff0000u);
    o1.z += wk * asf(v.w << 16); o1.w += wk * asf(v.w & 0xffff0000u);
  }
  *(float4*)(out + off) = o0;
  *(float4*)(out + off + 4) = o1;
}

extern "C" void kernel_launch(void* const* d_in, const int* in_sizes, int n_in,
                              void* d_out, int out_size, void* d_ws,
                              size_t ws_size, hipStream_t stream) {
  const float* x   = (const float*)d_in[0];
  const float* gw  = (const float*)d_in[1];
  const float* wgu = (const float*)d_in[2];
  const float* wd  = (const float*)d_in[3];
  const float* sgu = (const float*)d_in[4];
  const float* sd  = (const float*)d_in[5];
  float* out = (float*)d_out;

  char* ws = (char*)d_ws;
  int*   topk_id     = (int*)(ws + 0);
  float* topk_w      = (float*)(ws + 16384);
  int*   counts      = (int*)(ws + 32768);
  int*   offs        = (int*)(ws + 33792);
  int*   cum         = (int*)(ws + 34816);
  int*   tok_of_row  = (int*)(ws + 35840);
  int*   row_of_slot = (int*)(ws + 52224);
  uint16_t* x_bf     = (uint16_t*)(ws + 131072);
  uint16_t* act      = (uint16_t*)(ws + 4325376);
  float*    p0       = (float*)(ws + 4325376);     // aliases act (dead by then)
  uint16_t* yslots   = (uint16_t*)(ws + 15859712);
  uint16_t* act_sh   = (uint16_t*)(ws + 32636928);
  float*    p1       = (float*)(ws + 38404096);
  // p1 - p0 in floats: sk=1 output lands exactly at p1
  const long SPLIT_ELEMS = (38404096L - 4325376L) / 4;   // 8519680
  bool dosplit = ws_size >= (size_t)38404096 + 8388608;

  k_router<<<T_TOK, 256, 0, stream>>>(x, gw, topk_id, topk_w);
  k_count<<<E_NUM, 256, 0, stream>>>(topk_id, counts);
  k_offs<<<1, 1, 0, stream>>>(counts, offs, cum);
  k_fill<<<E_NUM, 256, 0, stream>>>(topk_id, offs, tok_of_row, row_of_slot);
  k_cvt<<<(T_TOK * H_DIM) / 1024, 256, 0, stream>>>(x, x_bf);

  // routed gate_up + silu*mul -> act[4096][1408]
  k_gemm<0, 64><<<48 * 22, 256, 0, stream>>>(
      x_bf, H_DIM, wgu, 2 * I_DIM, (long)H_DIM * 2 * I_DIM,
      act, I_DIM, offs, tok_of_row, cum, 0, H_DIM, I_DIM, 1, 0, 22);
  // routed down -> yslots[4096][2048]
  k_gemm<1, 128><<<48 * 16, 256, 0, stream>>>(
      act, I_DIM, wd, H_DIM, (long)I_DIM * H_DIM,
      yslots, H_DIM, offs, nullptr, cum, 0, I_DIM, 0, 1, 0, 16);
  // shared gate_up + silu*mul -> act_sh[1024][2816]
  k_gemm<0, 64><<<8 * 44, 256, 0, stream>>>(
      x_bf, H_DIM, sgu, 2 * SI_DIM, 0,
      act_sh, SI_DIM, nullptr, nullptr, nullptr, T_TOK, H_DIM, SI_DIM, 1, 0, 44);
  // shared down -> f32 partial(s)
  if (dosplit) {
    k_gemm<2, 64><<<8 * 32 * 2, 256, 0, stream>>>(
        act_sh, SI_DIM, sd, H_DIM, 0, p0, H_DIM,
        nullptr, nullptr, nullptr, T_TOK, SI_DIM, 0, 2, SPLIT_ELEMS, 32);
  } else {
    k_gemm<2, 64><<<8 * 32, 256, 0, stream>>>(
        act_sh, SI_DIM, sd, H_DIM, 0, p0, H_DIM,
        nullptr, nullptr, nullptr, T_TOK, SI_DIM, 0, 1, 0, 32);
  }
  // out = shared + weighted routed
  k_combine<<<T_TOK, 256, 0, stream>>>(out, yslots, row_of_slot, topk_w, p0,
                                       dosplit ? p1 : nullptr);
}

// Round 6
// 379.982 us; speedup vs baseline: 1.8935x; 1.0846x over previous
//
#include <hip/hip_runtime.h>
#include <hip/hip_bf16.h>
#include <stdint.h>
#include <math.h>

#define T_TOK 1024
#define H_DIM 2048
#define E_NUM 16
#define I_DIM 1408
#define TOPK  4
#define SI_DIM 2816
#define NSLOT (T_TOK * TOPK)

typedef short bf16x8 __attribute__((ext_vector_type(8)));
typedef float f32x4  __attribute__((ext_vector_type(4)));

__device__ __forceinline__ uint32_t fbf(float f) {
  __hip_bfloat16 h = __float2bfloat16(f);
  return (uint32_t)*reinterpret_cast<uint16_t*>(&h);
}
__device__ __forceinline__ float asf(uint32_t u) {
  union { uint32_t u; float f; } c; c.u = u; return c.f;
}

typedef const __attribute__((address_space(1))) char gld_g;
typedef __attribute__((address_space(3))) char gld_l;
__device__ __forceinline__ void gload16(const void* g, void* l) {
  __builtin_amdgcn_global_load_lds((gld_g*)g, (gld_l*)l, 16, 0, 0);
}

// ---------------- router ----------------
__global__ __launch_bounds__(256) void k_router(const float* __restrict__ x,
                                                const float* __restrict__ gw,
                                                int* __restrict__ topk_id,
                                                float* __restrict__ topk_w) {
  int t = blockIdx.x;
  float acc[E_NUM];
#pragma unroll
  for (int e = 0; e < E_NUM; ++e) acc[e] = 0.f;
  for (int h = threadIdx.x; h < H_DIM; h += 256) {
    float xv = x[(long)t * H_DIM + h];
#pragma unroll
    for (int e = 0; e < E_NUM; ++e) acc[e] += xv * gw[e * H_DIM + h];
  }
#pragma unroll
  for (int e = 0; e < E_NUM; ++e) {
#pragma unroll
    for (int off = 32; off; off >>= 1) acc[e] += __shfl_down(acc[e], off);
  }
  __shared__ float part[4][E_NUM];
  int wid = threadIdx.x >> 6, lane = threadIdx.x & 63;
  if (lane == 0) {
#pragma unroll
    for (int e = 0; e < E_NUM; ++e) part[wid][e] = acc[e];
  }
  __syncthreads();
  if (threadIdx.x == 0) {
    float lg[E_NUM], p[E_NUM];
    float m = -1e30f;
    for (int e = 0; e < E_NUM; ++e) {
      lg[e] = part[0][e] + part[1][e] + part[2][e] + part[3][e];
      m = fmaxf(m, lg[e]);
    }
    float s = 0.f;
    for (int e = 0; e < E_NUM; ++e) { p[e] = expf(lg[e] - m); s += p[e]; }
    float inv = 1.f / s;
    for (int e = 0; e < E_NUM; ++e) p[e] *= inv;
    float gs[4];
    for (int g = 0; g < 4; ++g) {
      float mg = p[g * 4];
      for (int i = 1; i < 4; ++i) mg = fmaxf(mg, p[g * 4 + i]);
      gs[g] = mg;
    }
    int g1 = 0;
    for (int g = 1; g < 4; ++g) if (gs[g] > gs[g1]) g1 = g;
    int g2 = -1;
    for (int g = 0; g < 4; ++g) {
      if (g == g1) continue;
      if (g2 < 0 || gs[g] > gs[g2]) g2 = g;
    }
    float q[E_NUM];
    for (int e = 0; e < E_NUM; ++e)
      q[e] = ((e >> 2) == g1 || (e >> 2) == g2) ? p[e] : -1e30f;
    int ids[TOPK]; float wv[TOPK]; float wsum = 0.f;
    for (int k = 0; k < TOPK; ++k) {
      int best = 0; float bv = -2e30f;
      for (int e = 0; e < E_NUM; ++e) if (q[e] > bv) { bv = q[e]; best = e; }
      ids[k] = best; wv[k] = p[best]; wsum += p[best]; q[best] = -3e30f;
    }
    float winv = 1.f / wsum;
    for (int k = 0; k < TOPK; ++k) {
      topk_id[t * TOPK + k] = ids[k];
      topk_w[t * TOPK + k] = wv[k] * winv;
    }
  }
}

// ---------------- per-expert counts ----------------
__global__ __launch_bounds__(256) void k_count(const int* __restrict__ topk_id,
                                               int* __restrict__ counts) {
  int e = blockIdx.x, tid = threadIdx.x;
  int c = 0;
  for (int s = tid; s < NSLOT; s += 256) c += (topk_id[s] == e);
#pragma unroll
  for (int off = 32; off; off >>= 1) c += __shfl_down(c, off);
  __shared__ int wsum[4];
  int wid = tid >> 6, lane = tid & 63;
  if (lane == 0) wsum[wid] = c;
  __syncthreads();
  if (tid == 0) counts[e] = wsum[0] + wsum[1] + wsum[2] + wsum[3];
}

__global__ void k_offs(const int* __restrict__ counts, int* __restrict__ offs,
                       int* __restrict__ cum) {
  if (threadIdx.x == 0 && blockIdx.x == 0) {
    int s = 0, c = 0;
    cum[0] = 0;
    for (int e = 0; e < E_NUM; ++e) {
      offs[e] = s; s += counts[e];
      c += (counts[e] + 127) >> 7;
      cum[e + 1] = c;
    }
    offs[E_NUM] = s;
  }
}

// ---------------- deterministic compaction ----------------
__global__ __launch_bounds__(256) void k_fill(const int* __restrict__ topk_id,
                                              const int* __restrict__ offs,
                                              int* __restrict__ tok_of_row,
                                              int* __restrict__ row_of_slot) {
  int e = blockIdx.x, tid = threadIdx.x;
  int t0 = tid * 4;
  int match[4]; int cnt = 0;
#pragma unroll
  for (int i = 0; i < 4; ++i) {
    int t = t0 + i; int mk = -1;
#pragma unroll
    for (int k = 0; k < TOPK; ++k) if (topk_id[t * TOPK + k] == e) mk = k;
    match[i] = mk; cnt += (mk >= 0);
  }
  __shared__ int sc[256];
  sc[tid] = cnt; __syncthreads();
  for (int d = 1; d < 256; d <<= 1) {
    int v = sc[tid];
    if (tid >= d) v += sc[tid - d];
    __syncthreads();
    sc[tid] = v;
    __syncthreads();
  }
  int row = offs[e] + sc[tid] - cnt;
#pragma unroll
  for (int i = 0; i < 4; ++i) {
    if (match[i] >= 0) {
      tok_of_row[row] = t0 + i;
      row_of_slot[(t0 + i) * TOPK + match[i]] = row;
      ++row;
    }
  }
}

// ---------------- x fp32 -> bf16 ----------------
__global__ __launch_bounds__(256) void k_cvt(const float* __restrict__ in,
                                             uint16_t* __restrict__ out) {
  int i = (blockIdx.x * 256 + threadIdx.x) * 4;
  float4 v = *(const float4*)(in + i);
  uint2 p;
  p.x = fbf(v.x) | (fbf(v.y) << 16);
  p.y = fbf(v.z) | (fbf(v.w) << 16);
  *(uint2*)(out + i) = p;
}

// ---------------- 128xBN MFMA GEMM, 512 thr, BK=64, merged 2 problems ------
// MODE 0: C = silu(A@Bg)*(A@Bu) -> bf16  (BN=64)
// MODE 1: C = A@B -> bf16 or f32 (flag)  (BN=128)
// blocks [0,NBs) = dense problem S; [NBs, ...) = routed problem R.
// rowlist (gather indirection) applies ONLY to the routed problem and ONLY
// when A is token-indexed (gate_up). Down-proj A is already compacted ->
// rowlist must be nullptr (R5 bug: passed tok_of_row -> wrong act rows).
template <int MODE>
__global__ __launch_bounds__(512, 4) void k_gemm(
    const uint16_t* __restrict__ As, int ldas,
    const float* __restrict__ Bs, int ldbs, int upS,
    void* __restrict__ OutS, int ldoS, int NMs, int Ks, int f32S,
    const uint16_t* __restrict__ Ar, int ldar,
    const float* __restrict__ Br, int ldbr, long bstr, int upR,
    void* __restrict__ OutR, int ldoR, int NN1, int K1, int f32R,
    const int* __restrict__ offs, const int* __restrict__ rowlist,
    const int* __restrict__ cum, int NBs) {
  constexpr int BN = (MODE == 0) ? 64 : 128;
  constexpr int NI = BN / 32;
  constexpr int BB = 16384;           // B region base within a buffer
  constexpr int HALF = 34816;         // 16K A + 18K B
  __shared__ char smem[2 * HALF];

  // ---- bijective chunked XCD swizzle over the merged grid ----
  int NB = gridDim.x, f = blockIdx.x;
  int q8 = NB >> 3, r8 = NB & 7;
  int xcd = f & 7, o = f >> 3;
  int f2 = (xcd < r8 ? xcd * (q8 + 1) : r8 * (q8 + 1) + (xcd - r8) * q8) + o;

  const uint16_t* A; const float* Bp; void* Outp; const int* rl;
  int lda, ldb, up, ldo, K, m0, n0, row_end, isf32;
  if (f2 < NBs) {
    int mb = f2 % NMs, nb = f2 / NMs;
    A = As; lda = ldas; Bp = Bs; ldb = ldbs; up = upS;
    Outp = OutS; ldo = ldoS; K = Ks; isf32 = f32S; rl = nullptr;
    m0 = mb * 128; row_end = NMs * 128; n0 = nb * BN;
  } else {
    int g = f2 - NBs;
    int e;
    for (e = 0; e < E_NUM; ++e) if (g < cum[e + 1] * NN1) break;
    if (e == E_NUM) return;
    int nmbe = cum[e + 1] - cum[e];
    int loc = g - cum[e] * NN1;
    int mb = loc % nmbe, nb = loc / nmbe;
    A = Ar; lda = ldar; Bp = Br + (size_t)e * bstr; ldb = ldbr; up = upR;
    Outp = OutR; ldo = ldoR; K = K1; isf32 = f32R; rl = rowlist;
    m0 = offs[e] + mb * 128; row_end = offs[e + 1]; n0 = nb * BN;
    if (m0 >= row_end) return;
  }

  const int tid = threadIdx.x;
  const int wid = tid >> 6, lane = tid & 63;
  const int wm = (wid >> 1) * 32, wn = (wid & 1) * (BN / 2);
  const int lrow = lane & 15, kg = lane >> 4;

  // ---- A staging (2 gload16/thread; wave-uniform dest; swizzled source) ----
  const uint16_t* aSrc[2]; int aDst[2];
#pragma unroll
  for (int p = 0; p < 2; ++p) {
    int r = wid * 16 + p * 8 + (lane >> 3);
    int c = (lane & 7) ^ (p * 4 + (lane >> 4));
    int grow = m0 + r;
    grow = grow < row_end - 1 ? grow : row_end - 1;
    int arow = rl ? rl[grow] : grow;
    aSrc[p] = A + (size_t)arow * lda + c * 8;
    aDst[p] = wid * 2048 + p * 1024;
  }

  // ---- B staging (4 dwordx4/thread -> 4 b64 LDS writes) ----
  int n4, kq, mat;
  if constexpr (MODE == 0) {
    n4 = (tid & 15) * 4; int sub = tid >> 4; mat = sub >> 4; kq = sub & 15;
  } else {
    n4 = (tid & 31) * 4; mat = 0; kq = tid >> 5;
  }
  const int k0 = kq * 4;
  const float* bsrc = Bp + (size_t)k0 * ldb + n0 + n4 + (mat ? up : 0);
  const int keyb = (n4 >> 4) & 7;
  const int cw = ((k0 >> 3) ^ keyb) << 4;
  const int halfo = (k0 & 4) << 1;
  int bwOff[4];
#pragma unroll
  for (int j = 0; j < 4; ++j)
    bwOff[j] = BB + mat * 9216 + (n4 + j) * 144 + cw + halfo;

  float4 v[4];
  auto loadB = [&]() {
#pragma unroll
    for (int i = 0; i < 4; ++i) v[i] = *(const float4*)(bsrc + (size_t)i * ldb);
    bsrc += (size_t)64 * ldb;
  };
  auto stageB = [&](int bufbase) {
#pragma unroll
    for (int j = 0; j < 4; ++j) {
      uint2 w;
      w.x = fbf(((const float*)&v[0])[j]) | (fbf(((const float*)&v[1])[j]) << 16);
      w.y = fbf(((const float*)&v[2])[j]) | (fbf(((const float*)&v[3])[j]) << 16);
      *(uint2*)(smem + bufbase + bwOff[j]) = w;
    }
  };

  f32x4 zero = {0.f, 0.f, 0.f, 0.f};
  f32x4 accg[2][NI];
  f32x4 accu[(MODE == 0) ? 2 : 1][(MODE == 0) ? NI : 1];
#pragma unroll
  for (int mi = 0; mi < 2; ++mi)
#pragma unroll
    for (int ni = 0; ni < NI; ++ni) {
      accg[mi][ni] = zero;
      if constexpr (MODE == 0) accu[mi][ni] = zero;
    }

  // ---- prologue ----
  loadB();
#pragma unroll
  for (int p = 0; p < 2; ++p) { gload16(aSrc[p], smem + aDst[p]); aSrc[p] += 64; }
  stageB(0);
  __syncthreads();

  const int nk = K >> 6;
  for (int kt = 0; kt < nk; ++kt) {
    const int cur = kt & 1;
    const char* base = smem + cur * HALF;
    const int obase = (cur ^ 1) * HALF;
    const bool pf = (kt + 1 < nk);
    if (pf) {
#pragma unroll
      for (int p = 0; p < 2; ++p) {
        gload16(aSrc[p], smem + obase + aDst[p]); aSrc[p] += 64;
      }
      loadB();
    }
#pragma unroll
    for (int ks = 0; ks < 2; ++ks) {
      bf16x8 af[2];
#pragma unroll
      for (int mi = 0; mi < 2; ++mi) {
        int row = wm + mi * 16 + lrow;
        af[mi] = *(const bf16x8*)(base + row * 128 +
                                  (((ks * 4 + kg) ^ (lrow >> 1)) << 4));
      }
#pragma unroll
      for (int ni = 0; ni < NI; ++ni) {
        int n = wn + ni * 16 + lrow;
        int kb = ((ks * 4 + kg) ^ (((wn >> 4) + ni) & 7)) << 4;
        bf16x8 bg = *(const bf16x8*)(base + BB + n * 144 + kb);
#pragma unroll
        for (int mi = 0; mi < 2; ++mi)
          accg[mi][ni] = __builtin_amdgcn_mfma_f32_16x16x32_bf16(
              af[mi], bg, accg[mi][ni], 0, 0, 0);
        if constexpr (MODE == 0) {
          bf16x8 bu = *(const bf16x8*)(base + BB + 9216 + n * 144 + kb);
#pragma unroll
          for (int mi = 0; mi < 2; ++mi)
            accu[mi][ni] = __builtin_amdgcn_mfma_f32_16x16x32_bf16(
                af[mi], bu, accu[mi][ni], 0, 0, 0);
        }
      }
    }
    if (pf) stageB(obase);
    __syncthreads();
  }

  // ---- epilogue: C/D layout col=lane&15, row=(lane>>4)*4+reg ----
#pragma unroll
  for (int mi = 0; mi < 2; ++mi) {
#pragma unroll
    for (int rr = 0; rr < 4; ++rr) {
      int grow = m0 + wm + mi * 16 + kg * 4 + rr;
      if (grow >= row_end) continue;
#pragma unroll
      for (int ni = 0; ni < NI; ++ni) {
        int col = n0 + wn + ni * 16 + lrow;
        float g = accg[mi][ni][rr];
        if constexpr (MODE == 0) {
          float u = accu[mi][ni][rr];
          float a = g / (1.f + __expf(-g)) * u;
          ((uint16_t*)Outp)[(size_t)grow * ldo + col] = (uint16_t)fbf(a);
        } else {
          if (isf32)
            ((float*)Outp)[(size_t)grow * ldo + col] = g;
          else
            ((uint16_t*)Outp)[(size_t)grow * ldo + col] = (uint16_t)fbf(g);
        }
      }
    }
  }
}

// ---------------- combine: out = p0 + sum_k w_k * y[slot] -------------------
__global__ __launch_bounds__(256) void k_combine(float* __restrict__ out,
    const uint16_t* __restrict__ y, const int* __restrict__ row_of_slot,
    const float* __restrict__ topk_w, const float* __restrict__ p0) {
  int t = blockIdx.x, tid = threadIdx.x;
  int h = tid * 8;
  size_t off = (size_t)t * H_DIM + h;
  float4 o0 = *(const float4*)(p0 + off);
  float4 o1 = *(const float4*)(p0 + off + 4);
#pragma unroll
  for (int k = 0; k < TOPK; ++k) {
    int row = row_of_slot[t * TOPK + k];
    float wk = topk_w[t * TOPK + k];
    uint4 v = *(const uint4*)(y + (size_t)row * H_DIM + h);
    o0.x += wk * asf(v.x << 16); o0.y += wk * asf(v.x & 0xffff0000u);
    o0.z += wk * asf(v.y << 16); o0.w += wk * asf(v.y & 0xffff0000u);
    o1.x += wk * asf(v.z << 16); o1.y += wk * asf(v.z & 0xffff0000u);
    o1.z += wk * asf(v.w << 16); o1.w += wk * asf(v.w & 0xffff0000u);
  }
  *(float4*)(out + off) = o0;
  *(float4*)(out + off + 4) = o1;
}

extern "C" void kernel_launch(void* const* d_in, const int* in_sizes, int n_in,
                              void* d_out, int out_size, void* d_ws,
                              size_t ws_size, hipStream_t stream) {
  const float* x   = (const float*)d_in[0];
  const float* gw  = (const float*)d_in[1];
  const float* wgu = (const float*)d_in[2];
  const float* wd  = (const float*)d_in[3];
  const float* sgu = (const float*)d_in[4];
  const float* sd  = (const float*)d_in[5];
  float* out = (float*)d_out;

  char* ws = (char*)d_ws;
  int*   topk_id     = (int*)(ws + 0);
  float* topk_w      = (float*)(ws + 16384);
  int*   counts      = (int*)(ws + 32768);
  int*   offs        = (int*)(ws + 33792);
  int*   cum         = (int*)(ws + 34816);
  int*   tok_of_row  = (int*)(ws + 35840);
  int*   row_of_slot = (int*)(ws + 52224);
  uint16_t* x_bf     = (uint16_t*)(ws + 131072);     //  4.19 MB
  uint16_t* act      = (uint16_t*)(ws + 4325376);    // 11.53 MB
  uint16_t* yslots   = (uint16_t*)(ws + 15859712);   // 16.78 MB
  uint16_t* act_sh   = (uint16_t*)(ws + 32636928);   //  5.77 MB
  // merged d2 needs p0 disjoint from act (routed-down reads act concurrently)
  bool merged = ws_size >= (size_t)38404096 + 8388608;
  float* p0 = merged ? (float*)(ws + 38404096) : (float*)(ws + 4325376);

  k_router<<<T_TOK, 256, 0, stream>>>(x, gw, topk_id, topk_w);
  k_count<<<E_NUM, 256, 0, stream>>>(topk_id, counts);
  k_offs<<<1, 1, 0, stream>>>(counts, offs, cum);
  k_fill<<<E_NUM, 256, 0, stream>>>(topk_id, offs, tok_of_row, row_of_slot);
  k_cvt<<<(T_TOK * H_DIM) / 1024, 256, 0, stream>>>(x, x_bf);

  // d1: shared gate_up (352 blocks) + routed gate_up (<=1056 blocks)
  //     routed A = x_bf (token-indexed) -> rowlist = tok_of_row
  k_gemm<0><<<352 + 48 * 22, 512, 0, stream>>>(
      x_bf, H_DIM, sgu, 2 * SI_DIM, SI_DIM, act_sh, SI_DIM, 8, H_DIM, 0,
      x_bf, H_DIM, wgu, 2 * I_DIM, (long)H_DIM * 2 * I_DIM, I_DIM,
      act, I_DIM, 22, H_DIM, 0,
      offs, tok_of_row, cum, 352);

  if (merged) {
    // d2: shared down (128 blocks, f32 out) + routed down (<=768 blocks)
    //     routed A = act (already compacted) -> rowlist = nullptr
    k_gemm<1><<<128 + 48 * 16, 512, 0, stream>>>(
        act_sh, SI_DIM, sd, H_DIM, 0, p0, H_DIM, 8, SI_DIM, 1,
        act, I_DIM, wd, H_DIM, (long)I_DIM * H_DIM, 0,
        yslots, H_DIM, 16, I_DIM, 0,
        offs, nullptr, cum, 128);
  } else {
    // fallback: routed down first (reads act), then shared down (p0 aliases act)
    k_gemm<1><<<48 * 16, 512, 0, stream>>>(
        act_sh, SI_DIM, sd, H_DIM, 0, p0, H_DIM, 8, SI_DIM, 1,
        act, I_DIM, wd, H_DIM, (long)I_DIM * H_DIM, 0,
        yslots, H_DIM, 16, I_DIM, 0,
        offs, nullptr, cum, 0);
    k_gemm<1><<<128, 512, 0, stream>>>(
        act_sh, SI_DIM, sd, H_DIM, 0, p0, H_DIM, 8, SI_DIM, 1,
        act, I_DIM, wd, H_DIM, (long)I_DIM * H_DIM, 0,
        yslots, H_DIM, 16, I_DIM, 0,
        offs, nullptr, cum, 128);
  }
  k_combine<<<T_TOK, 256, 0, stream>>>(out, yslots, row_of_slot, topk_w, p0);
}